// Round 22
// baseline (215.907 us; speedup 1.0000x reference)
//
#include <hip/hip_runtime.h>
#include <hip/hip_bf16.h>

// ---------------- constants ----------------
constexpr int B_ = 8, C_ = 128, Hh = 64, Ww = 64, L_ = Hh * Ww;   // L = 4096
constexpr int CIN_ = 192, K_ = 4, Rr = 8, DFF_ = 512;
constexpr long SZ1 = (long)B_ * C_ * L_;                           // 4,194,304 floats
constexpr float EPSf = 1e-5f;
constexpr float LOG2E = 1.44269504088896f;
constexpr float LN2f  = 0.693147180559945f;

#define DEVI __device__ __forceinline__

using s16x4 = __attribute__((ext_vector_type(4))) short;
using s16x8 = __attribute__((ext_vector_type(8))) short;
using f32x4 = __attribute__((ext_vector_type(4))) float;

DEVI float sigm(float x) { return 1.f / (1.f + __expf(-x)); }
DEVI float geluf(float x) { return 0.5f * x * (1.f + erff(x * 0.70710678118654752f)); }
DEVI float siluf(float x) { return x * sigm(x); }

// float -> bf16 bits (RNE) and back
DEVI unsigned short f2bf(float f) {
    unsigned u = __float_as_uint(f);
    u += 0x7fffu + ((u >> 16) & 1u);
    return (unsigned short)(u >> 16);
}
DEVI float bf2f(unsigned short u) { return __uint_as_float((unsigned)u << 16); }
DEVI float upk(const unsigned* p, int i) {
    unsigned v = p[i >> 1];
    return __uint_as_float((i & 1) ? (v & 0xffff0000u) : (v << 16));
}

// transposed-plane ("scan order") address of position pos in a 64x64 plane
DEVI int tadr(int pos) { return ((pos & 63) << 6) | (pos >> 6); }

// ---------------- bf16 MFMA tiled GEMM (+optional fused 2nd GEMM stage) ----------------
// F2=0: none. F2=1: 2nd GEMM W2 @ LN-normalized-output -> bf16 Out2 (ssm_in fusion).
// F2=2: 2nd GEMM W2 @ z (main output), g=sigm(+b2), Out2 = h + g*(z-h) (gate fusion).
// OGELU: apply exact GELU in epilogue before the bf16 store (moves GELU off the
//        consumer kernel's latency-bound staging path).
template <int BN, bool ACC, bool BIAS, bool XGELU, bool OGELU, bool SIG, bool GATE, bool SPLIT,
          bool XLN, bool LNOUT, bool XBF, bool OUTBF, int F2>
__global__ __launch_bounds__(256) void gemm_k(
    const float* __restrict__ W, const float* __restrict__ X1, long sX1,
    const float* __restrict__ X2, long sX2, int splitRow,
    const float* __restrict__ bias,
    const float* __restrict__ xmu, const float* __restrict__ xrs,
    const float* __restrict__ xg, const float* __restrict__ xbt,
    float* __restrict__ NOut, const float* __restrict__ og, const float* __restrict__ obt,
    float* __restrict__ Cp, long sC, int M, int N, int K,
    const float* __restrict__ W2, const float* __restrict__ b2,
    const float* __restrict__ Hres, float* __restrict__ Out2)
{
    constexpr int NI = BN / 32;
    __shared__ unsigned short sA[128][40];
    __shared__ unsigned short sB[BN][40];
    constexpr int F2S = (F2 > 0) ? (128 * 136 + 64 * 136) : 1;
    __shared__ unsigned short s2buf[F2S];   // [0,128*136) = W2 tile ; rest = Z tile
    const int tid = threadIdx.x;
    const int bn = blockIdx.x, bm = blockIdx.y, bz = blockIdx.z;
    const float* X1b = X1 + (XBF ? 0 : (long)bz * sX1);
    const unsigned short* X1u = XBF ? ((const unsigned short*)X1 + (long)bz * sX1) : nullptr;
    const float* X2b = (SPLIT || GATE) ? (X2 + (long)bz * sX2) : nullptr;
    float* Cb = Cp + (long)bz * sC;
    unsigned short* Cu = OUTBF ? ((unsigned short*)Cp + (long)bz * sC) : nullptr;
    const int n0 = bn * BN, m0 = bm * 128;

    const int l = tid & 63, w = tid >> 6;
    const int wm = w >> 1, wn = w & 1;
    const int lr = l & 15, lk = (l >> 4) * 8;

    const int awrow = tid >> 1, awk = (tid & 1) * 16;

    f32x4 acc[4][NI];
#pragma unroll
    for (int i = 0; i < 4; i++)
#pragma unroll
        for (int j = 0; j < NI; j++) acc[i][j] = (f32x4)0.f;

    for (int k0 = 0; k0 < K; k0 += 32) {
        {
            const float* wp = W + (long)(m0 + awrow) * K + k0 + awk;
            float4 f0 = *(const float4*)(wp + 0);
            float4 f1 = *(const float4*)(wp + 4);
            float4 f2 = *(const float4*)(wp + 8);
            float4 f3 = *(const float4*)(wp + 12);
            s16x8 v0, v1;
            v0[0]=f2bf(f0.x); v0[1]=f2bf(f0.y); v0[2]=f2bf(f0.z); v0[3]=f2bf(f0.w);
            v0[4]=f2bf(f1.x); v0[5]=f2bf(f1.y); v0[6]=f2bf(f1.z); v0[7]=f2bf(f1.w);
            v1[0]=f2bf(f2.x); v1[1]=f2bf(f2.y); v1[2]=f2bf(f2.z); v1[3]=f2bf(f2.w);
            v1[4]=f2bf(f3.x); v1[5]=f2bf(f3.y); v1[6]=f2bf(f3.z); v1[7]=f2bf(f3.w);
            *(s16x8*)&sA[awrow][awk] = v0;
            *(s16x8*)&sA[awrow][awk + 8] = v1;
        }
        if constexpr (BN == 128) {
            const int bnb = tid & 31, bkb = tid >> 5;
            const int krow = k0 + bkb * 4;
            const int colk = n0 + bnb * 4;
            float4 r0, r1, r2, r3;
            if constexpr (XBF) {
                ushort4 a0 = *(const ushort4*)(X1u + (long)krow * N + colk);
                ushort4 a1 = *(const ushort4*)(X1u + (long)(krow + 1) * N + colk);
                ushort4 a2 = *(const ushort4*)(X1u + (long)(krow + 2) * N + colk);
                ushort4 a3 = *(const ushort4*)(X1u + (long)(krow + 3) * N + colk);
                r0 = make_float4(bf2f(a0.x), bf2f(a0.y), bf2f(a0.z), bf2f(a0.w));
                r1 = make_float4(bf2f(a1.x), bf2f(a1.y), bf2f(a1.z), bf2f(a1.w));
                r2 = make_float4(bf2f(a2.x), bf2f(a2.y), bf2f(a2.z), bf2f(a2.w));
                r3 = make_float4(bf2f(a3.x), bf2f(a3.y), bf2f(a3.z), bf2f(a3.w));
            } else {
                const float* xp;
                if (SPLIT && krow >= splitRow)
                    xp = X2b + (long)(krow - splitRow) * N + colk;
                else
                    xp = X1b + (long)krow * N + colk;
                r0 = *(const float4*)(xp + 0 * (long)N);
                r1 = *(const float4*)(xp + 1 * (long)N);
                r2 = *(const float4*)(xp + 2 * (long)N);
                r3 = *(const float4*)(xp + 3 * (long)N);
            }
            if (XGELU) {
                r0.x=geluf(r0.x); r0.y=geluf(r0.y); r0.z=geluf(r0.z); r0.w=geluf(r0.w);
                r1.x=geluf(r1.x); r1.y=geluf(r1.y); r1.z=geluf(r1.z); r1.w=geluf(r1.w);
                r2.x=geluf(r2.x); r2.y=geluf(r2.y); r2.z=geluf(r2.z); r2.w=geluf(r2.w);
                r3.x=geluf(r3.x); r3.y=geluf(r3.y); r3.z=geluf(r3.z); r3.w=geluf(r3.w);
            }
            const float* p0 = (const float*)&r0;
            const float* p1 = (const float*)&r1;
            const float* p2 = (const float*)&r2;
            const float* p3 = (const float*)&r3;
#pragma unroll
            for (int c = 0; c < 4; c++) {
                s16x4 v;
                v[0] = f2bf(p0[c]); v[1] = f2bf(p1[c]);
                v[2] = f2bf(p2[c]); v[3] = f2bf(p3[c]);
                *(s16x4*)&sB[bnb * 4 + c][bkb * 4] = v;
            }
        } else {
            const int bnb = tid & 15, bkb = tid >> 4;
            const int krow = k0 + bkb * 2;
            const int col0 = n0 + bnb * 4;
            float4 r0, r1;
            if constexpr (XBF) {
                ushort4 a0 = *(const ushort4*)(X1u + (long)krow * N + col0);
                ushort4 a1 = *(const ushort4*)(X1u + (long)(krow + 1) * N + col0);
                r0 = make_float4(bf2f(a0.x), bf2f(a0.y), bf2f(a0.z), bf2f(a0.w));
                r1 = make_float4(bf2f(a1.x), bf2f(a1.y), bf2f(a1.z), bf2f(a1.w));
            } else {
                const float* xpa;
                const float* xpb;
                if (SPLIT && krow >= splitRow)
                    xpa = X2b + (long)(krow - splitRow) * N + col0;
                else
                    xpa = X1b + (long)krow * N + col0;
                if (SPLIT && (krow + 1) >= splitRow)
                    xpb = X2b + (long)(krow + 1 - splitRow) * N + col0;
                else
                    xpb = X1b + (long)(krow + 1) * N + col0;
                r0 = *(const float4*)xpa;
                r1 = *(const float4*)xpb;
            }
            if (XLN) {
                float4 m4 = *(const float4*)(xmu + (long)bz * N + col0);
                float4 s4 = *(const float4*)(xrs + (long)bz * N + col0);
                float ga = xg[krow], be = xbt[krow];
                r0.x=(r0.x-m4.x)*s4.x*ga+be; r0.y=(r0.y-m4.y)*s4.y*ga+be;
                r0.z=(r0.z-m4.z)*s4.z*ga+be; r0.w=(r0.w-m4.w)*s4.w*ga+be;
                ga = xg[krow + 1]; be = xbt[krow + 1];
                r1.x=(r1.x-m4.x)*s4.x*ga+be; r1.y=(r1.y-m4.y)*s4.y*ga+be;
                r1.z=(r1.z-m4.z)*s4.z*ga+be; r1.w=(r1.w-m4.w)*s4.w*ga+be;
            }
            if (XGELU) {
                r0.x=geluf(r0.x); r0.y=geluf(r0.y); r0.z=geluf(r0.z); r0.w=geluf(r0.w);
                r1.x=geluf(r1.x); r1.y=geluf(r1.y); r1.z=geluf(r1.z); r1.w=geluf(r1.w);
            }
            const float* p0 = (const float*)&r0;
            const float* p1 = (const float*)&r1;
#pragma unroll
            for (int c = 0; c < 4; c++) {
                unsigned v = (unsigned)f2bf(p0[c]) | ((unsigned)f2bf(p1[c]) << 16);
                *(unsigned*)&sB[bnb * 4 + c][bkb * 2] = v;
            }
        }
        __syncthreads();
        s16x8 af[4], bfr[NI];
#pragma unroll
        for (int mi = 0; mi < 4; mi++) af[mi] = *(const s16x8*)&sA[wm * 64 + mi * 16 + lr][lk];
#pragma unroll
        for (int ni = 0; ni < NI; ni++) bfr[ni] = *(const s16x8*)&sB[wn * (BN / 2) + ni * 16 + lr][lk];
#pragma unroll
        for (int mi = 0; mi < 4; mi++)
#pragma unroll
            for (int ni = 0; ni < NI; ni++)
                acc[mi][ni] = __builtin_amdgcn_mfma_f32_16x16x32_bf16(af[mi], bfr[ni], acc[mi][ni], 0, 0, 0);
        __syncthreads();
    }

    float ps[NI], pq[NI];
    if (LNOUT) {
#pragma unroll
        for (int ni = 0; ni < NI; ni++) { ps[ni] = 0.f; pq[ni] = 0.f; }
    }
#pragma unroll
    for (int mi = 0; mi < 4; mi++) {
#pragma unroll
        for (int r = 0; r < 4; r++) {
            const int row = m0 + wm * 64 + mi * 16 + (l >> 4) * 4 + r;
            const float bv = BIAS ? bias[row] : 0.f;
#pragma unroll
            for (int ni = 0; ni < NI; ni++) {
                const int colL = wn * (BN / 2) + ni * 16 + lr;
                const int col = n0 + colL;
                float v = acc[mi][ni][r] + bv;
                if constexpr (OUTBF) {
                    float vv = v;
                    if (OGELU) vv = geluf(vv);
                    Cu[(long)row * N + col] = f2bf(vv);
                } else {
                    float* cp = Cb + (long)row * N + col;
                    if (ACC) v += *cp;
                    if (SIG) v = sigm(v);
                    if (GATE) {
                        v = sigm(v);
                        float zv = X1b[(long)row * N + col];
                        float hv = X2b[(long)row * N + col];
                        v = hv + v * (zv - hv);
                    }
                    if constexpr (F2 == 2) {
                        s2buf[128 * 136 + colL * 136 + row] = f2bf(v);
                        acc[mi][ni][r] = v;
                    } else {
                        *cp = v;
                    }
                }
                if (LNOUT) {
                    acc[mi][ni][r] = v;
                    ps[ni] += v; pq[ni] += v * v;
                }
            }
        }
    }
    if constexpr (LNOUT) {
        __shared__ float redS[2][2][NI][16];
        __shared__ float redQ[2][2][NI][16];
        __shared__ float muL[BN], rsL[BN];
#pragma unroll
        for (int ni = 0; ni < NI; ni++) {
            ps[ni] += __shfl_xor(ps[ni], 16, 64);
            ps[ni] += __shfl_xor(ps[ni], 32, 64);
            pq[ni] += __shfl_xor(pq[ni], 16, 64);
            pq[ni] += __shfl_xor(pq[ni], 32, 64);
        }
        if (l < 16) {
#pragma unroll
            for (int ni = 0; ni < NI; ni++) {
                redS[wm][wn][ni][l] = ps[ni];
                redQ[wm][wn][ni][l] = pq[ni];
            }
        }
        __syncthreads();
        if (tid < BN) {
            const int cc = tid;
            const int wn2 = cc >> 5, rem = cc & 31;
            const int ni2 = rem >> 4, lr2 = rem & 15;
            float s = redS[0][wn2][ni2][lr2] + redS[1][wn2][ni2][lr2];
            float q = redQ[0][wn2][ni2][lr2] + redQ[1][wn2][ni2][lr2];
            float mu = s * (1.f / 128.f);
            float var = q * (1.f / 128.f) - mu * mu;
            muL[cc] = mu;
            rsL[cc] = rsqrtf(var + EPSf);
        }
        __syncthreads();
        unsigned short* Nb = (unsigned short*)NOut + (long)bz * sC;
#pragma unroll
        for (int mi = 0; mi < 4; mi++) {
#pragma unroll
            for (int r = 0; r < 4; r++) {
                const int row = m0 + wm * 64 + mi * 16 + (l >> 4) * 4 + r;
                const float gg = og[row], bb = obt[row];
#pragma unroll
                for (int ni = 0; ni < NI; ni++) {
                    const int cc = wn * (BN / 2) + ni * 16 + lr;
                    const int col = n0 + cc;
                    float v = acc[mi][ni][r];
                    float nv = (v - muL[cc]) * rsL[cc] * gg + bb;
                    if constexpr (F2 == 1)
                        s2buf[128 * 136 + cc * 136 + row] = f2bf(nv);
                    else
                        Nb[(long)row * N + col] = f2bf(nv);
                }
            }
        }
    }
    // ---- fused 2nd GEMM stage (M=128, single bm, BN=64 required) ----
    if constexpr (F2 > 0) {
        {
            const int r2 = tid >> 1, kk = (tid & 1) * 16;
#pragma unroll
            for (int q = 0; q < 4; q++) {
                const float* wp = W2 + (long)r2 * 128 + q * 32 + kk;
                float4 f0 = *(const float4*)(wp + 0);
                float4 f1 = *(const float4*)(wp + 4);
                float4 f2 = *(const float4*)(wp + 8);
                float4 f3 = *(const float4*)(wp + 12);
                s16x8 v0, v1;
                v0[0]=f2bf(f0.x); v0[1]=f2bf(f0.y); v0[2]=f2bf(f0.z); v0[3]=f2bf(f0.w);
                v0[4]=f2bf(f1.x); v0[5]=f2bf(f1.y); v0[6]=f2bf(f1.z); v0[7]=f2bf(f1.w);
                v1[0]=f2bf(f2.x); v1[1]=f2bf(f2.y); v1[2]=f2bf(f2.z); v1[3]=f2bf(f2.w);
                v1[4]=f2bf(f3.x); v1[5]=f2bf(f3.y); v1[6]=f2bf(f3.z); v1[7]=f2bf(f3.w);
                *(s16x8*)&s2buf[r2 * 136 + q * 32 + kk] = v0;
                *(s16x8*)&s2buf[r2 * 136 + q * 32 + kk + 8] = v1;
            }
        }
        __syncthreads();
        f32x4 acc2[4][2];
#pragma unroll
        for (int i = 0; i < 4; i++) { acc2[i][0] = (f32x4)0.f; acc2[i][1] = (f32x4)0.f; }
#pragma unroll
        for (int k0 = 0; k0 < 4; k0++) {
            s16x8 af2[4], bf2[2];
#pragma unroll
            for (int mi = 0; mi < 4; mi++)
                af2[mi] = *(const s16x8*)&s2buf[(wm * 64 + mi * 16 + lr) * 136 + k0 * 32 + lk];
#pragma unroll
            for (int ni = 0; ni < 2; ni++)
                bf2[ni] = *(const s16x8*)&s2buf[128 * 136 + (wn * 32 + ni * 16 + lr) * 136 + k0 * 32 + lk];
#pragma unroll
            for (int mi = 0; mi < 4; mi++)
#pragma unroll
                for (int ni = 0; ni < 2; ni++)
                    acc2[mi][ni] = __builtin_amdgcn_mfma_f32_16x16x32_bf16(af2[mi], bf2[ni], acc2[mi][ni], 0, 0, 0);
        }
#pragma unroll
        for (int mi = 0; mi < 4; mi++) {
#pragma unroll
            for (int r = 0; r < 4; r++) {
                const int row = wm * 64 + mi * 16 + (l >> 4) * 4 + r;
#pragma unroll
                for (int ni = 0; ni < 2; ni++) {
                    const int col = n0 + wn * 32 + ni * 16 + lr;
                    float v2 = acc2[mi][ni][r];
                    if constexpr (F2 == 1) {
                        ((unsigned short*)Out2 + (long)bz * sC)[(long)row * N + col] = f2bf(v2);
                    } else {
                        float g = sigm(v2 + b2[row]);
                        float zv = acc[mi][ni][r];
                        float hv = Hres[(long)bz * sC + (long)row * N + col];
                        (Out2 + (long)bz * sC)[(long)row * N + col] = hv + g * (zv - hv);
                    }
                }
            }
        }
    }
}

// ---------------- channel-LN stats on bf16 input ----------------
__global__ __launch_bounds__(256) void ln_stats_k(const unsigned short* __restrict__ in,
                                                  float* __restrict__ mu,
                                                  float* __restrict__ rs)
{
    __shared__ float s1[4][64], s2[4][64];
    const int tid = threadIdx.x;
    const int p = tid & 63, q = tid >> 6;
    const long posg = (long)blockIdx.x * 64 + p;
    const int b = (int)(posg / L_);
    const int pp = (int)(posg % L_);
    const unsigned short* base = in + ((long)b * C_ + q * 32) * L_ + pp;
    float s = 0.f, sq = 0.f;
#pragma unroll
    for (int i = 0; i < 32; i++) {
        float t = bf2f(base[(long)i * L_]);
        s += t; sq += t * t;
    }
    s1[q][p] = s; s2[q][p] = sq;
    __syncthreads();
    if (q == 0) {
        float ts = s1[0][p] + s1[1][p] + s1[2][p] + s1[3][p];
        float tq = s2[0][p] + s2[1][p] + s2[2][p] + s2[3][p];
        float m = ts * (1.f / 128.f);
        float var = tq * (1.f / 128.f) - m * m;
        mu[posg] = m;
        rs[posg] = rsqrtf(var + EPSf);
    }
}

// ---------------- fused depthwise 3x3 + SiLU (bf16 in/out) ----------------
__global__ __launch_bounds__(256) void dwconvT_k(const unsigned short* __restrict__ in,
                                                 const float* __restrict__ wts,
                                                 const float* __restrict__ bias,
                                                 unsigned short* __restrict__ uo,
                                                 unsigned short* __restrict__ uTo)
{
    __shared__ float t[64][65];
    const long plane = blockIdx.x;
    const int c = (int)(plane & 127);
    const int tid = threadIdx.x;
    const unsigned short* src = in + plane * (long)L_;
#pragma unroll
    for (int ii = 0; ii < 16; ii++) {
        int idx = tid + ii * 256;
        t[idx >> 6][idx & 63] = bf2f(src[idx]);
    }
    float kw[9];
#pragma unroll
    for (int q = 0; q < 9; q++) kw[q] = wts[c * 9 + q];
    const float bc = bias[c];
    __syncthreads();
    float r[16];
#pragma unroll
    for (int ii = 0; ii < 16; ii++) {
        int idx = tid + ii * 256;
        int h = idx >> 6, w2 = idx & 63;
        float acc = bc;
#pragma unroll
        for (int dh = -1; dh <= 1; dh++) {
            int hh = h + dh;
            if ((unsigned)hh >= 64u) continue;
#pragma unroll
            for (int dw = -1; dw <= 1; dw++) {
                int ww2 = w2 + dw;
                if ((unsigned)ww2 >= 64u) continue;
                acc += t[hh][ww2] * kw[(dh + 1) * 3 + (dw + 1)];
            }
        }
        r[ii] = siluf(acc);
    }
    __syncthreads();
    unsigned short* ud = uo + plane * (long)L_;
#pragma unroll
    for (int ii = 0; ii < 16; ii++) {
        int idx = tid + ii * 256;
        t[idx >> 6][idx & 63] = r[ii];
        ud[idx] = f2bf(r[ii]);
    }
    __syncthreads();
    unsigned short* utd = uTo + plane * (long)L_;
#pragma unroll
    for (int ii = 0; ii < 16; ii++) {
        int idx = tid + ii * 256;
        utd[idx] = f2bf(t[idx & 63][idx >> 6]);
    }
}

// ---------------- per-plane 64x64 bf16 transpose-add ----------------
__global__ __launch_bounds__(256) void transpb_k(const unsigned short* __restrict__ src,
                                                 unsigned short* __restrict__ dst)
{
    __shared__ float t[64][65];
    const long plane = blockIdx.x;
    const unsigned short* s = src + plane * (long)L_;
    unsigned short* d = dst + plane * (long)L_;
    const int tid = threadIdx.x;
#pragma unroll
    for (int i = 0; i < 16; i++) {
        int idx = tid + i * 256;
        t[idx >> 6][idx & 63] = bf2f(s[idx]);
    }
    __syncthreads();
#pragma unroll
    for (int i = 0; i < 16; i++) {
        int idx = tid + i * 256;
        int r = idx >> 6, cc = idx & 63;
        float val = t[cc][r] + bf2f(d[idx]);
        d[idx] = f2bf(val);
    }
}

// ---------------- x_dbl projection (bf16 u), k & k+2 fused (scan-order out) ----------------
__global__ __launch_bounds__(256) void xdbl2_k(const unsigned short* __restrict__ u,
                                               const unsigned short* __restrict__ uT,
                                               const float* __restrict__ xw,
                                               float* __restrict__ out)
{
    __shared__ float wsm[2][16][132];
    const int pair = blockIdx.y, b = blockIdx.z;
    const int tid = threadIdx.x;
#pragma unroll
    for (int i = 0; i < 8; i++) {
        int idx = tid * 8 + i;
        wsm[0][idx >> 7][idx & 127] = xw[pair * 2048 + idx];
        wsm[1][idx >> 7][idx & 127] = xw[(pair + 2) * 2048 + idx];
    }
    __syncthreads();
    const int dg = (tid & 3) * 4;
    const int lo = tid >> 2;
    const int pos = blockIdx.x * 64 + lo;
    const unsigned short* usrc = (pair ? uT : u) + (long)b * C_ * L_ + pos;
    float a0[4] = {0.f, 0.f, 0.f, 0.f};
    float a1[4] = {0.f, 0.f, 0.f, 0.f};
#pragma unroll 4
    for (int c = 0; c < C_; c++) {
        float uc = bf2f(usrc[(long)c * L_]);
#pragma unroll
        for (int j = 0; j < 4; j++) {
            a0[j] += wsm[0][dg + j][c] * uc;
            a1[j] += wsm[1][dg + j][c] * uc;
        }
    }
    const long baseA = ((long)(b * K_ + pair) * L_) << 4;
    const long baseB = ((long)(b * K_ + pair + 2) * L_) << 4;
    const int s  = tadr(pos);
    const int s2 = tadr(L_ - 1 - pos);
    *(float4*)(out + baseA + ((long)s  << 4) + dg) = make_float4(a0[0], a0[1], a0[2], a0[3]);
    *(float4*)(out + baseB + ((long)s2 << 4) + dg) = make_float4(a1[0], a1[1], a1[2], a1[3]);
}

// ---------------- scan pass 1 (stores wv bf16; P via exp2 of wv-sum) ----------------
template <bool WV>
__global__ __launch_bounds__(256) void scan_ph1L_k(const float* __restrict__ xdbl,
                                                   const unsigned short* __restrict__ u,
                                                   const unsigned short* __restrict__ uT,
                                                   const float* __restrict__ dtw,
                                                   const float* __restrict__ dtb,
                                                   const float* __restrict__ alogs,
                                                   float* __restrict__ st,
                                                   unsigned short* __restrict__ wvb)
{
    __shared__ float xtf[2][32][12];
    __shared__ float xtb[2][32][12];
    const int bid = blockIdx.x;
    const int jj = bid & 63, kh = (bid >> 6) & 1, b = bid >> 7;
    const int t = threadIdx.x;
    const int kf = kh, kb = kh + 2;
    const float* xf = xdbl + ((long)(b * 4 + kf) << 16);
    const float* xb = xdbl + ((long)(b * 4 + kb) << 16);
    {
        const int q = t & 3, i = (t >> 2) & 31, j2 = t >> 7;
        if (q < 3) {
            const int jf = 2 * jj + j2, jB = 127 - jf;
            const int sf = (((jf & 1) * 32 + i) << 6) | (jf >> 1);
            const int sb = (((jB & 1) * 32 + i) << 6) | (jB >> 1);
            *(float4*)&xtf[j2][i][q * 4] = *(const float4*)(xf + (long)sf * 16 + q * 4);
            *(float4*)&xtb[j2][i][q * 4] = *(const float4*)(xb + (long)sb * 16 + q * 4);
        }
    }
    const int c = t & 127, jh = t >> 7;
    const int jf = 2 * jj + jh, jB = 127 - jf;
    const unsigned short* uplane = (kh ? uT : u) + (long)(b * 128 + c) * L_;
    unsigned ur2[16];
    {
        const unsigned short* up = uplane + jf * 32;
#pragma unroll
        for (int q = 0; q < 4; q++) {
            uint4 a = *(const uint4*)(up + q * 8);
            ur2[q * 4 + 0] = a.x; ur2[q * 4 + 1] = a.y;
            ur2[q * 4 + 2] = a.z; ur2[q * 4 + 3] = a.w;
        }
    }
    __syncthreads();
    unsigned wv2[16];
    // ---- fwd chunk ----
    {
        float dw[8];
#pragma unroll
        for (int r = 0; r < 8; r++) dw[r] = dtw[((kf * 128 + c) << 3) + r];
        const float db = dtb[kf * 128 + c];
        float An[4];
#pragma unroll
        for (int n = 0; n < 4; n++) An[n] = -__expf(alogs[((kf * 128 + c) << 2) + n]);
        float wsum = 0.f;
        float S0 = 0.f, S1 = 0.f, S2 = 0.f, S3 = 0.f;
#pragma unroll
        for (int i = 0; i < 32; i++) {
            float4 x0 = *(const float4*)&xtf[jh][i][0];
            float4 x1 = *(const float4*)&xtf[jh][i][4];
            float4 xs = *(const float4*)&xtf[jh][i][8];
            float z = db + x0.x*dw[0] + x0.y*dw[1] + x0.z*dw[2] + x0.w*dw[3]
                         + x1.x*dw[4] + x1.y*dw[5] + x1.z*dw[6] + x1.w*dw[7];
            float wv = (z > 15.f) ? z * LOG2E : log2f(1.f + __expf(z));
            unsigned short wb = f2bf(wv);
            wv = bf2f(wb);
            if (i & 1) wv2[i >> 1] |= ((unsigned)wb << 16);
            else       wv2[i >> 1]  = (unsigned)wb;
            wsum += wv;
            float dl = wv * LN2f;
            float du = dl * upk(ur2, i);
            float e;
            e = exp2f(wv * An[0]); S0 = e * S0 + du * xs.x;
            e = exp2f(wv * An[1]); S1 = e * S1 + du * xs.y;
            e = exp2f(wv * An[2]); S2 = e * S2 + du * xs.z;
            e = exp2f(wv * An[3]); S3 = e * S3 + du * xs.w;
        }
        float* o = st + ((long)((b * 4 + kf) * 128 + c) << 10) + (jf << 3);
        *(float4*)o = make_float4(exp2f(wsum * An[0]), exp2f(wsum * An[1]),
                                  exp2f(wsum * An[2]), exp2f(wsum * An[3]));
        *(float4*)(o + 4) = make_float4(S0, S1, S2, S3);
        if constexpr (WV) {
            unsigned short* wd = wvb + ((long)((b * 4 + kf) * 128 + c) << 12) + jf * 32;
#pragma unroll
            for (int q = 0; q < 4; q++)
                *(uint4*)(wd + q * 8) = make_uint4(wv2[q*4], wv2[q*4+1], wv2[q*4+2], wv2[q*4+3]);
        }
    }
    // ---- bwd chunk ----
    {
        float dw[8];
#pragma unroll
        for (int r = 0; r < 8; r++) dw[r] = dtw[((kb * 128 + c) << 3) + r];
        const float db = dtb[kb * 128 + c];
        float An[4];
#pragma unroll
        for (int n = 0; n < 4; n++) An[n] = -__expf(alogs[((kb * 128 + c) << 2) + n]);
        float wsum = 0.f;
        float S0 = 0.f, S1 = 0.f, S2 = 0.f, S3 = 0.f;
#pragma unroll
        for (int i = 0; i < 32; i++) {
            float4 x0 = *(const float4*)&xtb[jh][i][0];
            float4 x1 = *(const float4*)&xtb[jh][i][4];
            float4 xs = *(const float4*)&xtb[jh][i][8];
            float z = db + x0.x*dw[0] + x0.y*dw[1] + x0.z*dw[2] + x0.w*dw[3]
                         + x1.x*dw[4] + x1.y*dw[5] + x1.z*dw[6] + x1.w*dw[7];
            float wv = (z > 15.f) ? z * LOG2E : log2f(1.f + __expf(z));
            unsigned short wb = f2bf(wv);
            wv = bf2f(wb);
            if (i & 1) wv2[i >> 1] |= ((unsigned)wb << 16);
            else       wv2[i >> 1]  = (unsigned)wb;
            wsum += wv;
            float dl = wv * LN2f;
            float du = dl * upk(ur2, 31 - i);
            float e;
            e = exp2f(wv * An[0]); S0 = e * S0 + du * xs.x;
            e = exp2f(wv * An[1]); S1 = e * S1 + du * xs.y;
            e = exp2f(wv * An[2]); S2 = e * S2 + du * xs.z;
            e = exp2f(wv * An[3]); S3 = e * S3 + du * xs.w;
        }
        float* o = st + ((long)((b * 4 + kb) * 128 + c) << 10) + (jB << 3);
        *(float4*)o = make_float4(exp2f(wsum * An[0]), exp2f(wsum * An[1]),
                                  exp2f(wsum * An[2]), exp2f(wsum * An[3]));
        *(float4*)(o + 4) = make_float4(S0, S1, S2, S3);
        if constexpr (WV) {
            unsigned short* wd = wvb + ((long)((b * 4 + kb) * 128 + c) << 12) + jB * 32;
#pragma unroll
            for (int q = 0; q < 4; q++)
                *(uint4*)(wd + q * 8) = make_uint4(wv2[q*4], wv2[q*4+1], wv2[q*4+2], wv2[q*4+3]);
        }
    }
}

// ---------------- scan mid: wave scans 128 chunks (2 per lane) ----------------
__global__ __launch_bounds__(256) void scan_mid_k(float* __restrict__ st)
{
    const long t = (long)blockIdx.x * 256 + threadIdx.x;
    const long chain = t >> 6;
    const int ln = (int)(t & 63);
    float* base = st + (chain << 10) + (ln << 4);
    float4 Pa = *(float4*)(base + 0);
    float4 Sa = *(float4*)(base + 4);
    float4 Pb = *(float4*)(base + 8);
    float4 Sb = *(float4*)(base + 12);
    float4 P, S;
    P.x = Pb.x * Pa.x; P.y = Pb.y * Pa.y; P.z = Pb.z * Pa.z; P.w = Pb.w * Pa.w;
    S.x = Sb.x + Pb.x * Sa.x; S.y = Sb.y + Pb.y * Sa.y;
    S.z = Sb.z + Pb.z * Sa.z; S.w = Sb.w + Pb.w * Sa.w;
#pragma unroll
    for (int d = 1; d < 64; d <<= 1) {
        float4 Pu, Su;
        Pu.x = __shfl_up(P.x, d, 64); Pu.y = __shfl_up(P.y, d, 64);
        Pu.z = __shfl_up(P.z, d, 64); Pu.w = __shfl_up(P.w, d, 64);
        Su.x = __shfl_up(S.x, d, 64); Su.y = __shfl_up(S.y, d, 64);
        Su.z = __shfl_up(S.z, d, 64); Su.w = __shfl_up(S.w, d, 64);
        if (ln >= d) {
            S.x += P.x * Su.x; S.y += P.y * Su.y;
            S.z += P.z * Su.z; S.w += P.w * Su.w;
            P.x *= Pu.x; P.y *= Pu.y; P.z *= Pu.z; P.w *= Pu.w;
        }
    }
    float4 E;
    E.x = __shfl_up(S.x, 1, 64); E.y = __shfl_up(S.y, 1, 64);
    E.z = __shfl_up(S.z, 1, 64); E.w = __shfl_up(S.w, 1, 64);
    if (ln == 0) { E.x = 0.f; E.y = 0.f; E.z = 0.f; E.w = 0.f; }
    float4 E1;
    E1.x = Sa.x + Pa.x * E.x; E1.y = Sa.y + Pa.y * E.y;
    E1.z = Sa.z + Pa.z * E.z; E1.w = Sa.w + Pa.w * E.w;
    *(float4*)(base + 4)  = E;
    *(float4*)(base + 12) = E1;
}

// ---------------- scan pass 2: y in registers, direct bf16 global write ----------------
template <bool WV>
__global__ __launch_bounds__(256) void scan_ph2L_k(const float* __restrict__ xdbl,
                                                   const unsigned short* __restrict__ u,
                                                   const unsigned short* __restrict__ uT,
                                                   const float* __restrict__ dtw,
                                                   const float* __restrict__ dtb,
                                                   const float* __restrict__ alogs,
                                                   const float* __restrict__ Dsp,
                                                   const float* __restrict__ st,
                                                   const unsigned short* __restrict__ wvb,
                                                   unsigned short* __restrict__ Y0,
                                                   unsigned short* __restrict__ Yt)
{
    constexpr int TS = WV ? 8 : 16;
    __shared__ float xtf[2][32][TS];
    __shared__ float xtb[2][32][TS];
    const int bid = blockIdx.x;
    const int jj = bid & 63, kh = (bid >> 6) & 1, b = bid >> 7;
    const int t = threadIdx.x;
    const int kf = kh, kb = kh + 2;
    const float* xf = xdbl + ((long)(b * 4 + kf) << 16);
    const float* xb = xdbl + ((long)(b * 4 + kb) << 16);
    if constexpr (WV) {
        const int tt = t & 127;
        const int q = tt & 1, i = (tt >> 1) & 31, j2 = tt >> 6;
        const int jf2 = 2 * jj + j2, jB2 = 127 - jf2;
        if (t < 128) {
            const int sf = (((jf2 & 1) * 32 + i) << 6) | (jf2 >> 1);
            *(float4*)&xtf[j2][i][q * 4] = *(const float4*)(xf + (long)sf * 16 + 8 + q * 4);
        } else {
            const int sb = (((jB2 & 1) * 32 + i) << 6) | (jB2 >> 1);
            *(float4*)&xtb[j2][i][q * 4] = *(const float4*)(xb + (long)sb * 16 + 8 + q * 4);
        }
    } else {
        const int q = t & 3, i = (t >> 2) & 31, j2 = t >> 7;
        const int jf2 = 2 * jj + j2, jB2 = 127 - jf2;
        const int sf = (((jf2 & 1) * 32 + i) << 6) | (jf2 >> 1);
        const int sb = (((jB2 & 1) * 32 + i) << 6) | (jB2 >> 1);
        *(float4*)&xtf[j2][i][q * 4] = *(const float4*)(xf + (long)sf * 16 + q * 4);
        *(float4*)&xtb[j2][i][q * 4] = *(const float4*)(xb + (long)sb * 16 + q * 4);
    }
    const int c = t & 127, jh = t >> 7;
    const int jf = 2 * jj + jh, jB = 127 - jf;
    const unsigned short* uplane = (kh ? uT : u) + (long)(b * 128 + c) * L_;
    unsigned ur2[16];
    {
        const unsigned short* up = uplane + jf * 32;
#pragma unroll
        for (int q = 0; q < 4; q++) {
            uint4 a = *(const uint4*)(up + q * 8);
            ur2[q * 4 + 0] = a.x; ur2[q * 4 + 1] = a.y;
            ur2[q * 4 + 2] = a.z; ur2[q * 4 + 3] = a.w;
        }
    }
    __syncthreads();
    float yreg[32];
    unsigned wv2[16];
    // ---- fwd chunk ----
    {
        float An[4];
#pragma unroll
        for (int n = 0; n < 4; n++) An[n] = -__expf(alogs[((kf * 128 + c) << 2) + n]);
        const float Dc = Dsp[kf * 128 + c];
        float dw[8]; float db = 0.f;
        if constexpr (!WV) {
#pragma unroll
            for (int r = 0; r < 8; r++) dw[r] = dtw[((kf * 128 + c) << 3) + r];
            db = dtb[kf * 128 + c];
        } else {
            const unsigned short* wp2 = wvb + ((long)((b * 4 + kf) * 128 + c) << 12) + jf * 32;
#pragma unroll
            for (int q = 0; q < 4; q++) {
                uint4 a = *(const uint4*)(wp2 + q * 8);
                wv2[q * 4 + 0] = a.x; wv2[q * 4 + 1] = a.y;
                wv2[q * 4 + 2] = a.z; wv2[q * 4 + 3] = a.w;
            }
        }
        float4 H = *(const float4*)(st + ((long)((b * 4 + kf) * 128 + c) << 10) + (jf << 3) + 4);
        float h0 = H.x, h1 = H.y, h2 = H.z, h3 = H.w;
#pragma unroll
        for (int i = 0; i < 32; i++) {
            float wv;
            if constexpr (WV) {
                wv = upk(wv2, i);
            } else {
                float4 x0 = *(const float4*)&xtf[jh][i][0];
                float4 x1 = *(const float4*)&xtf[jh][i][4];
                float z = db + x0.x*dw[0] + x0.y*dw[1] + x0.z*dw[2] + x0.w*dw[3]
                             + x1.x*dw[4] + x1.y*dw[5] + x1.z*dw[6] + x1.w*dw[7];
                wv = (z > 15.f) ? z * LOG2E : log2f(1.f + __expf(z));
            }
            float4 xs = *(const float4*)&xtf[jh][i][TS - 8];
            float4 xc = *(const float4*)&xtf[jh][i][TS - 4];
            float uv = upk(ur2, i);
            float dl = wv * LN2f;
            float du = dl * uv;
            float e;
            e = exp2f(wv * An[0]); h0 = e * h0 + du * xs.x;
            e = exp2f(wv * An[1]); h1 = e * h1 + du * xs.y;
            e = exp2f(wv * An[2]); h2 = e * h2 + du * xs.z;
            e = exp2f(wv * An[3]); h3 = e * h3 + du * xs.w;
            yreg[i] = h0 * xc.x + h1 * xc.y + h2 * xc.z + h3 * xc.w + Dc * uv;
        }
    }
    // ---- bwd chunk (same 32 output positions, reversed) ----
    {
        float An[4];
#pragma unroll
        for (int n = 0; n < 4; n++) An[n] = -__expf(alogs[((kb * 128 + c) << 2) + n]);
        const float Dc = Dsp[kb * 128 + c];
        float dw[8]; float db = 0.f;
        if constexpr (!WV) {
#pragma unroll
            for (int r = 0; r < 8; r++) dw[r] = dtw[((kb * 128 + c) << 3) + r];
            db = dtb[kb * 128 + c];
        } else {
            const unsigned short* wp2 = wvb + ((long)((b * 4 + kb) * 128 + c) << 12) + jB * 32;
#pragma unroll
            for (int q = 0; q < 4; q++) {
                uint4 a = *(const uint4*)(wp2 + q * 8);
                wv2[q * 4 + 0] = a.x; wv2[q * 4 + 1] = a.y;
                wv2[q * 4 + 2] = a.z; wv2[q * 4 + 3] = a.w;
            }
        }
        float4 H = *(const float4*)(st + ((long)((b * 4 + kb) * 128 + c) << 10) + (jB << 3) + 4);
        float h0 = H.x, h1 = H.y, h2 = H.z, h3 = H.w;
#pragma unroll
        for (int i = 0; i < 32; i++) {
            float wv;
            if constexpr (WV) {
                wv = upk(wv2, i);
            } else {
                float4 x0 = *(const float4*)&xtb[jh][i][0];
                float4 x1 = *(const float4*)&xtb[jh][i][4];
                float z = db + x0.x*dw[0] + x0.y*dw[1] + x0.z*dw[2] + x0.w*dw[3]
                             + x1.x*dw[4] + x1.y*dw[5] + x1.z*dw[6] + x1.w*dw[7];
                wv = (z > 15.f) ? z * LOG2E : log2f(1.f + __expf(z));
            }
            float4 xs = *(const float4*)&xtb[jh][i][TS - 8];
            float4 xc = *(const float4*)&xtb[jh][i][TS - 4];
            float uv = upk(ur2, 31 - i);
            float dl = wv * LN2f;
            float du = dl * uv;
            float e;
            e = exp2f(wv * An[0]); h0 = e * h0 + du * xs.x;
            e = exp2f(wv * An[1]); h1 = e * h1 + du * xs.y;
            e = exp2f(wv * An[2]); h2 = e * h2 + du * xs.z;
            e = exp2f(wv * An[3]); h3 = e * h3 + du * xs.w;
            yreg[31 - i] += h0 * xc.x + h1 * xc.y + h2 * xc.z + h3 * xc.w + Dc * uv;
        }
    }
    unsigned short* ydst = (kh ? Yt : Y0) + (long)(b * 128 + c) * L_ + jf * 32;
#pragma unroll
    for (int q = 0; q < 8; q++) {
        ushort4 v;
        v.x = f2bf(yreg[q * 4 + 0]); v.y = f2bf(yreg[q * 4 + 1]);
        v.z = f2bf(yreg[q * 4 + 2]); v.w = f2bf(yreg[q * 4 + 3]);
        *(ushort4*)(ydst + q * 4) = v;
    }
}

// ---------------- launch ----------------
extern "C" void kernel_launch(void* const* d_in, const int* in_sizes, int n_in,
                              void* d_out, int out_size, void* d_ws, size_t ws_size,
                              hipStream_t stream)
{
    const float* h_in      = (const float*)d_in[0];
    const float* x_in      = (const float*)d_in[4];
    const float* in_proj_w = (const float*)d_in[5];
    const float* in_proj_b = (const float*)d_in[6];
    const float* ln1_g     = (const float*)d_in[7];
    const float* ln1_b     = (const float*)d_in[8];
    const float* ssm_in_w  = (const float*)d_in[9];
    const float* conv_w    = (const float*)d_in[10];
    const float* conv_b    = (const float*)d_in[11];
    const float* x_proj_w  = (const float*)d_in[12];
    const float* dt_w      = (const float*)d_in[13];
    const float* dt_b      = (const float*)d_in[14];
    const float* A_logs    = (const float*)d_in[15];
    const float* Dsp       = (const float*)d_in[16];
    const float* outnorm_g = (const float*)d_in[17];
    const float* outnorm_b = (const float*)d_in[18];
    const float* out_proj_w= (const float*)d_in[19];
    const float* ln2_g     = (const float*)d_in[20];
    const float* ln2_b     = (const float*)d_in[21];
    const float* fc1_w     = (const float*)d_in[22];
    const float* fc1_b     = (const float*)d_in[23];
    const float* fc2_w     = (const float*)d_in[24];
    const float* fc2_b     = (const float*)d_in[25];
    const float* gate_w    = (const float*)d_in[26];
    const float* gate_b    = (const float*)d_in[27];

    float* ws   = (float*)d_ws;
    float* fz   = ws;              // feat -> z (fp32)
    float* ubuf = ws + SZ1;        // u (bf16) ; MLP hidden (bf16) overlays
    float* tbuf = ws + 2 * SZ1;    // u0(bf16) -> Y0/merged-y (bf16)
    float* ybuf = ws + 3 * SZ1;    // uT(bf16)
    float* xdbl = ws + 4 * SZ1;    // [B,K,L(scan order),16] fp32
    float* stbf = ws + 4 * SZ1 + 2097152;           // chunk states
    float* muB  = stbf;            // LN stats overlay
    float* rsB  = stbf + 32768;
    const long wvOff = 4 * SZ1 + 2097152 + 4194304;
    unsigned short* wvb = (unsigned short*)(ws + wvOff);
    const bool wvOK = (ws_size / 4) >= (size_t)(wvOff + 8388608);
    float* mbuf = ubuf;            // MLP hidden, bf16, all 8 batches
    float* gbuf = (float*)d_out;   // Yt(bf16) -> ln2out(bf16) -> final out

    unsigned short* u_u  = (unsigned short*)ubuf;
    unsigned short* u0_u = (unsigned short*)tbuf;
    unsigned short* uT_u = (unsigned short*)ybuf;
    unsigned short* y0_u = (unsigned short*)tbuf;
    unsigned short* yt_u = (unsigned short*)gbuf;

    const dim3 blk(256);
    const long sBC = (long)C_ * L_;
    const long sX  = (long)CIN_ * L_;
    const long sM  = (long)DFF_ * L_;

    // 1) feat = in_proj@concat + b (fz); fused ln1 + ssm_in -> u0 (tbuf bf16)
    gemm_k<64, false, true, false, false, false, false, true, false, true, false, false, 1>
        <<<dim3(64, 1, 8), blk, 0, stream>>>(
        in_proj_w, h_in, sBC, x_in, sX, 128, in_proj_b,
        nullptr, nullptr, nullptr, nullptr, nullptr, ln1_g, ln1_b,
        fz, sBC, 128, L_, 320,
        ssm_in_w, nullptr, nullptr, tbuf);
    // 2) u = silu(dwconv(u0)+b) -> ubuf ; u^T -> ybuf
    dwconvT_k<<<dim3(1024), blk, 0, stream>>>(u0_u, conv_w, conv_b, u_u, uT_u);
    // 3) x_dbl, k & k+2 fused
    xdbl2_k<<<dim3(64, 2, 8), blk, 0, stream>>>(u_u, uT_u, x_proj_w, xdbl);
    // 4-6) scan
    if (wvOK) {
        scan_ph1L_k<true><<<dim3(1024), blk, 0, stream>>>(xdbl, u_u, uT_u, dt_w, dt_b,
                                                          A_logs, stbf, wvb);
        scan_mid_k<<<dim3(1024), blk, 0, stream>>>(stbf);
        scan_ph2L_k<true><<<dim3(1024), blk, 0, stream>>>(xdbl, u_u, uT_u, dt_w, dt_b,
                                                          A_logs, Dsp, stbf, wvb, y0_u, yt_u);
    } else {
        scan_ph1L_k<false><<<dim3(1024), blk, 0, stream>>>(xdbl, u_u, uT_u, dt_w, dt_b,
                                                           A_logs, stbf, wvb);
        scan_mid_k<<<dim3(1024), blk, 0, stream>>>(stbf);
        scan_ph2L_k<false><<<dim3(1024), blk, 0, stream>>>(xdbl, u_u, uT_u, dt_w, dt_b,
                                                           A_logs, Dsp, stbf, wvb, y0_u, yt_u);
    }
    // 7) merged y: tbuf += transpose(gbuf)
    transpb_k<<<dim3(1024), blk, 0, stream>>>(yt_u, y0_u);
    // 8) outnorm stats
    ln_stats_k<<<dim3(512), blk, 0, stream>>>(y0_u, muB, rsB);
    // 9) z = feat + out_proj @ outnorm(y) [XBF+XLN]; fused ln2 -> gbuf (bf16)
    gemm_k<64, true, false, false, false, false, false, false, true, true, true, false, 0>
        <<<dim3(64, 1, 8), blk, 0, stream>>>(
        out_proj_w, tbuf, sBC, nullptr, 0, 1 << 30, nullptr,
        muB, rsB, outnorm_g, outnorm_b, gbuf, ln2_g, ln2_b,
        fz, sBC, 128, L_, 128,
        nullptr, nullptr, nullptr, nullptr);
    // 10) fc1: all 8 batches, X = ln2out bf16 -> hidden bf16 (GELU fused in epilogue)
    gemm_k<128, false, true, false, true, false, false, false, false, false, true, true, 0>
        <<<dim3(32, 4, 8), blk, 0, stream>>>(
        fc1_w, gbuf, sBC, nullptr, 0, 1 << 30, fc1_b,
        nullptr, nullptr, nullptr, nullptr, nullptr, nullptr, nullptr,
        mbuf, sM, 512, L_, 128,
        nullptr, nullptr, nullptr, nullptr);
    // 11) fc2 (hidden already GELU'd; ACC z) ; fused gate GEMM + blend -> d_out
    gemm_k<64, true, true, false, false, false, false, false, false, false, true, false, 2>
        <<<dim3(64, 1, 8), blk, 0, stream>>>(
        fc2_w, mbuf, sM, nullptr, 0, 1 << 30, fc2_b,
        nullptr, nullptr, nullptr, nullptr, nullptr, nullptr, nullptr,
        fz, sBC, 128, L_, 512,
        gate_w, gate_b, h_in, (float*)d_out);
}

// Round 23
// 210.585 us; speedup vs baseline: 1.0253x; 1.0253x over previous
//
#include <hip/hip_runtime.h>
#include <hip/hip_bf16.h>

// ---------------- constants ----------------
constexpr int B_ = 8, C_ = 128, Hh = 64, Ww = 64, L_ = Hh * Ww;   // L = 4096
constexpr int CIN_ = 192, K_ = 4, Rr = 8, DFF_ = 512;
constexpr long SZ1 = (long)B_ * C_ * L_;                           // 4,194,304 floats
constexpr float EPSf = 1e-5f;
constexpr float LOG2E = 1.44269504088896f;
constexpr float LN2f  = 0.693147180559945f;

#define DEVI __device__ __forceinline__

using s16x4 = __attribute__((ext_vector_type(4))) short;
using s16x8 = __attribute__((ext_vector_type(8))) short;
using f32x4 = __attribute__((ext_vector_type(4))) float;

DEVI float sigm(float x) { return 1.f / (1.f + __expf(-x)); }
DEVI float geluf(float x) { return 0.5f * x * (1.f + erff(x * 0.70710678118654752f)); }
DEVI float siluf(float x) { return x * sigm(x); }

// float -> bf16 bits (RNE) and back
DEVI unsigned short f2bf(float f) {
    unsigned u = __float_as_uint(f);
    u += 0x7fffu + ((u >> 16) & 1u);
    return (unsigned short)(u >> 16);
}
DEVI float bf2f(unsigned short u) { return __uint_as_float((unsigned)u << 16); }
DEVI float upk(const unsigned* p, int i) {
    unsigned v = p[i >> 1];
    return __uint_as_float((i & 1) ? (v & 0xffff0000u) : (v << 16));
}

// transposed-plane ("scan order") address of position pos in a 64x64 plane
DEVI int tadr(int pos) { return ((pos & 63) << 6) | (pos >> 6); }

// ---------------- bf16 MFMA tiled GEMM (+optional fused 2nd GEMM stage) ----------------
// F2=0: none. F2=1: 2nd GEMM W2 @ LN-normalized-output -> bf16 Out2 (ssm_in fusion).
// F2=2: 2nd GEMM W2 @ z (main output), g=sigm(+b2), Out2 = h + g*(z-h) (gate fusion).
template <int BN, bool ACC, bool BIAS, bool XGELU, bool SIG, bool GATE, bool SPLIT,
          bool XLN, bool LNOUT, bool XBF, bool OUTBF, int F2>
__global__ __launch_bounds__(256) void gemm_k(
    const float* __restrict__ W, const float* __restrict__ X1, long sX1,
    const float* __restrict__ X2, long sX2, int splitRow,
    const float* __restrict__ bias,
    const float* __restrict__ xmu, const float* __restrict__ xrs,
    const float* __restrict__ xg, const float* __restrict__ xbt,
    float* __restrict__ NOut, const float* __restrict__ og, const float* __restrict__ obt,
    float* __restrict__ Cp, long sC, int M, int N, int K,
    const float* __restrict__ W2, const float* __restrict__ b2,
    const float* __restrict__ Hres, float* __restrict__ Out2)
{
    constexpr int NI = BN / 32;
    __shared__ unsigned short sA[128][40];
    __shared__ unsigned short sB[BN][40];
    constexpr int F2S = (F2 > 0) ? (128 * 136 + 64 * 136) : 1;
    __shared__ unsigned short s2buf[F2S];   // [0,128*136) = W2 tile ; rest = Z tile
    const int tid = threadIdx.x;
    const int bn = blockIdx.x, bm = blockIdx.y, bz = blockIdx.z;
    const float* X1b = X1 + (XBF ? 0 : (long)bz * sX1);
    const unsigned short* X1u = XBF ? ((const unsigned short*)X1 + (long)bz * sX1) : nullptr;
    const float* X2b = (SPLIT || GATE) ? (X2 + (long)bz * sX2) : nullptr;
    float* Cb = Cp + (long)bz * sC;
    unsigned short* Cu = OUTBF ? ((unsigned short*)Cp + (long)bz * sC) : nullptr;
    const int n0 = bn * BN, m0 = bm * 128;

    const int l = tid & 63, w = tid >> 6;
    const int wm = w >> 1, wn = w & 1;
    const int lr = l & 15, lk = (l >> 4) * 8;

    const int awrow = tid >> 1, awk = (tid & 1) * 16;

    f32x4 acc[4][NI];
#pragma unroll
    for (int i = 0; i < 4; i++)
#pragma unroll
        for (int j = 0; j < NI; j++) acc[i][j] = (f32x4)0.f;

    for (int k0 = 0; k0 < K; k0 += 32) {
        {
            const float* wp = W + (long)(m0 + awrow) * K + k0 + awk;
            float4 f0 = *(const float4*)(wp + 0);
            float4 f1 = *(const float4*)(wp + 4);
            float4 f2 = *(const float4*)(wp + 8);
            float4 f3 = *(const float4*)(wp + 12);
            s16x8 v0, v1;
            v0[0]=f2bf(f0.x); v0[1]=f2bf(f0.y); v0[2]=f2bf(f0.z); v0[3]=f2bf(f0.w);
            v0[4]=f2bf(f1.x); v0[5]=f2bf(f1.y); v0[6]=f2bf(f1.z); v0[7]=f2bf(f1.w);
            v1[0]=f2bf(f2.x); v1[1]=f2bf(f2.y); v1[2]=f2bf(f2.z); v1[3]=f2bf(f2.w);
            v1[4]=f2bf(f3.x); v1[5]=f2bf(f3.y); v1[6]=f2bf(f3.z); v1[7]=f2bf(f3.w);
            *(s16x8*)&sA[awrow][awk] = v0;
            *(s16x8*)&sA[awrow][awk + 8] = v1;
        }
        if constexpr (BN == 128) {
            const int bnb = tid & 31, bkb = tid >> 5;
            const int krow = k0 + bkb * 4;
            const int colk = n0 + bnb * 4;
            float4 r0, r1, r2, r3;
            if constexpr (XBF) {
                ushort4 a0 = *(const ushort4*)(X1u + (long)krow * N + colk);
                ushort4 a1 = *(const ushort4*)(X1u + (long)(krow + 1) * N + colk);
                ushort4 a2 = *(const ushort4*)(X1u + (long)(krow + 2) * N + colk);
                ushort4 a3 = *(const ushort4*)(X1u + (long)(krow + 3) * N + colk);
                r0 = make_float4(bf2f(a0.x), bf2f(a0.y), bf2f(a0.z), bf2f(a0.w));
                r1 = make_float4(bf2f(a1.x), bf2f(a1.y), bf2f(a1.z), bf2f(a1.w));
                r2 = make_float4(bf2f(a2.x), bf2f(a2.y), bf2f(a2.z), bf2f(a2.w));
                r3 = make_float4(bf2f(a3.x), bf2f(a3.y), bf2f(a3.z), bf2f(a3.w));
            } else {
                const float* xp;
                if (SPLIT && krow >= splitRow)
                    xp = X2b + (long)(krow - splitRow) * N + colk;
                else
                    xp = X1b + (long)krow * N + colk;
                r0 = *(const float4*)(xp + 0 * (long)N);
                r1 = *(const float4*)(xp + 1 * (long)N);
                r2 = *(const float4*)(xp + 2 * (long)N);
                r3 = *(const float4*)(xp + 3 * (long)N);
            }
            if (XGELU) {
                r0.x=geluf(r0.x); r0.y=geluf(r0.y); r0.z=geluf(r0.z); r0.w=geluf(r0.w);
                r1.x=geluf(r1.x); r1.y=geluf(r1.y); r1.z=geluf(r1.z); r1.w=geluf(r1.w);
                r2.x=geluf(r2.x); r2.y=geluf(r2.y); r2.z=geluf(r2.z); r2.w=geluf(r2.w);
                r3.x=geluf(r3.x); r3.y=geluf(r3.y); r3.z=geluf(r3.z); r3.w=geluf(r3.w);
            }
            const float* p0 = (const float*)&r0;
            const float* p1 = (const float*)&r1;
            const float* p2 = (const float*)&r2;
            const float* p3 = (const float*)&r3;
#pragma unroll
            for (int c = 0; c < 4; c++) {
                s16x4 v;
                v[0] = f2bf(p0[c]); v[1] = f2bf(p1[c]);
                v[2] = f2bf(p2[c]); v[3] = f2bf(p3[c]);
                *(s16x4*)&sB[bnb * 4 + c][bkb * 4] = v;
            }
        } else {
            const int bnb = tid & 15, bkb = tid >> 4;
            const int krow = k0 + bkb * 2;
            const int col0 = n0 + bnb * 4;
            float4 r0, r1;
            if constexpr (XBF) {
                ushort4 a0 = *(const ushort4*)(X1u + (long)krow * N + col0);
                ushort4 a1 = *(const ushort4*)(X1u + (long)(krow + 1) * N + col0);
                r0 = make_float4(bf2f(a0.x), bf2f(a0.y), bf2f(a0.z), bf2f(a0.w));
                r1 = make_float4(bf2f(a1.x), bf2f(a1.y), bf2f(a1.z), bf2f(a1.w));
            } else {
                const float* xpa;
                const float* xpb;
                if (SPLIT && krow >= splitRow)
                    xpa = X2b + (long)(krow - splitRow) * N + col0;
                else
                    xpa = X1b + (long)krow * N + col0;
                if (SPLIT && (krow + 1) >= splitRow)
                    xpb = X2b + (long)(krow + 1 - splitRow) * N + col0;
                else
                    xpb = X1b + (long)(krow + 1) * N + col0;
                r0 = *(const float4*)xpa;
                r1 = *(const float4*)xpb;
            }
            if (XLN) {
                float4 m4 = *(const float4*)(xmu + (long)bz * N + col0);
                float4 s4 = *(const float4*)(xrs + (long)bz * N + col0);
                float ga = xg[krow], be = xbt[krow];
                r0.x=(r0.x-m4.x)*s4.x*ga+be; r0.y=(r0.y-m4.y)*s4.y*ga+be;
                r0.z=(r0.z-m4.z)*s4.z*ga+be; r0.w=(r0.w-m4.w)*s4.w*ga+be;
                ga = xg[krow + 1]; be = xbt[krow + 1];
                r1.x=(r1.x-m4.x)*s4.x*ga+be; r1.y=(r1.y-m4.y)*s4.y*ga+be;
                r1.z=(r1.z-m4.z)*s4.z*ga+be; r1.w=(r1.w-m4.w)*s4.w*ga+be;
            }
            if (XGELU) {
                r0.x=geluf(r0.x); r0.y=geluf(r0.y); r0.z=geluf(r0.z); r0.w=geluf(r0.w);
                r1.x=geluf(r1.x); r1.y=geluf(r1.y); r1.z=geluf(r1.z); r1.w=geluf(r1.w);
            }
            const float* p0 = (const float*)&r0;
            const float* p1 = (const float*)&r1;
#pragma unroll
            for (int c = 0; c < 4; c++) {
                unsigned v = (unsigned)f2bf(p0[c]) | ((unsigned)f2bf(p1[c]) << 16);
                *(unsigned*)&sB[bnb * 4 + c][bkb * 2] = v;
            }
        }
        __syncthreads();
        s16x8 af[4], bfr[NI];
#pragma unroll
        for (int mi = 0; mi < 4; mi++) af[mi] = *(const s16x8*)&sA[wm * 64 + mi * 16 + lr][lk];
#pragma unroll
        for (int ni = 0; ni < NI; ni++) bfr[ni] = *(const s16x8*)&sB[wn * (BN / 2) + ni * 16 + lr][lk];
#pragma unroll
        for (int mi = 0; mi < 4; mi++)
#pragma unroll
            for (int ni = 0; ni < NI; ni++)
                acc[mi][ni] = __builtin_amdgcn_mfma_f32_16x16x32_bf16(af[mi], bfr[ni], acc[mi][ni], 0, 0, 0);
        __syncthreads();
    }

    float ps[NI], pq[NI];
    if (LNOUT) {
#pragma unroll
        for (int ni = 0; ni < NI; ni++) { ps[ni] = 0.f; pq[ni] = 0.f; }
    }
#pragma unroll
    for (int mi = 0; mi < 4; mi++) {
#pragma unroll
        for (int r = 0; r < 4; r++) {
            const int row = m0 + wm * 64 + mi * 16 + (l >> 4) * 4 + r;
            const float bv = BIAS ? bias[row] : 0.f;
#pragma unroll
            for (int ni = 0; ni < NI; ni++) {
                const int colL = wn * (BN / 2) + ni * 16 + lr;
                const int col = n0 + colL;
                float v = acc[mi][ni][r] + bv;
                if constexpr (OUTBF) {
                    Cu[(long)row * N + col] = f2bf(v);
                } else {
                    float* cp = Cb + (long)row * N + col;
                    if (ACC) v += *cp;
                    if (SIG) v = sigm(v);
                    if (GATE) {
                        v = sigm(v);
                        float zv = X1b[(long)row * N + col];
                        float hv = X2b[(long)row * N + col];
                        v = hv + v * (zv - hv);
                    }
                    if constexpr (F2 == 2) {
                        s2buf[128 * 136 + colL * 136 + row] = f2bf(v);
                        acc[mi][ni][r] = v;
                    } else {
                        *cp = v;
                    }
                }
                if (LNOUT) {
                    acc[mi][ni][r] = v;
                    ps[ni] += v; pq[ni] += v * v;
                }
            }
        }
    }
    if constexpr (LNOUT) {
        __shared__ float redS[2][2][NI][16];
        __shared__ float redQ[2][2][NI][16];
        __shared__ float muL[BN], rsL[BN];
#pragma unroll
        for (int ni = 0; ni < NI; ni++) {
            ps[ni] += __shfl_xor(ps[ni], 16, 64);
            ps[ni] += __shfl_xor(ps[ni], 32, 64);
            pq[ni] += __shfl_xor(pq[ni], 16, 64);
            pq[ni] += __shfl_xor(pq[ni], 32, 64);
        }
        if (l < 16) {
#pragma unroll
            for (int ni = 0; ni < NI; ni++) {
                redS[wm][wn][ni][l] = ps[ni];
                redQ[wm][wn][ni][l] = pq[ni];
            }
        }
        __syncthreads();
        if (tid < BN) {
            const int cc = tid;
            const int wn2 = cc >> 5, rem = cc & 31;
            const int ni2 = rem >> 4, lr2 = rem & 15;
            float s = redS[0][wn2][ni2][lr2] + redS[1][wn2][ni2][lr2];
            float q = redQ[0][wn2][ni2][lr2] + redQ[1][wn2][ni2][lr2];
            float mu = s * (1.f / 128.f);
            float var = q * (1.f / 128.f) - mu * mu;
            muL[cc] = mu;
            rsL[cc] = rsqrtf(var + EPSf);
        }
        __syncthreads();
        unsigned short* Nb = (unsigned short*)NOut + (long)bz * sC;
#pragma unroll
        for (int mi = 0; mi < 4; mi++) {
#pragma unroll
            for (int r = 0; r < 4; r++) {
                const int row = m0 + wm * 64 + mi * 16 + (l >> 4) * 4 + r;
                const float gg = og[row], bb = obt[row];
#pragma unroll
                for (int ni = 0; ni < NI; ni++) {
                    const int cc = wn * (BN / 2) + ni * 16 + lr;
                    const int col = n0 + cc;
                    float v = acc[mi][ni][r];
                    float nv = (v - muL[cc]) * rsL[cc] * gg + bb;
                    if constexpr (F2 == 1)
                        s2buf[128 * 136 + cc * 136 + row] = f2bf(nv);
                    else
                        Nb[(long)row * N + col] = f2bf(nv);
                }
            }
        }
    }
    // ---- fused 2nd GEMM stage (M=128, single bm, BN=64 required) ----
    if constexpr (F2 > 0) {
        {
            const int r2 = tid >> 1, kk = (tid & 1) * 16;
#pragma unroll
            for (int q = 0; q < 4; q++) {
                const float* wp = W2 + (long)r2 * 128 + q * 32 + kk;
                float4 f0 = *(const float4*)(wp + 0);
                float4 f1 = *(const float4*)(wp + 4);
                float4 f2 = *(const float4*)(wp + 8);
                float4 f3 = *(const float4*)(wp + 12);
                s16x8 v0, v1;
                v0[0]=f2bf(f0.x); v0[1]=f2bf(f0.y); v0[2]=f2bf(f0.z); v0[3]=f2bf(f0.w);
                v0[4]=f2bf(f1.x); v0[5]=f2bf(f1.y); v0[6]=f2bf(f1.z); v0[7]=f2bf(f1.w);
                v1[0]=f2bf(f2.x); v1[1]=f2bf(f2.y); v1[2]=f2bf(f2.z); v1[3]=f2bf(f2.w);
                v1[4]=f2bf(f3.x); v1[5]=f2bf(f3.y); v1[6]=f2bf(f3.z); v1[7]=f2bf(f3.w);
                *(s16x8*)&s2buf[r2 * 136 + q * 32 + kk] = v0;
                *(s16x8*)&s2buf[r2 * 136 + q * 32 + kk + 8] = v1;
            }
        }
        __syncthreads();
        f32x4 acc2[4][2];
#pragma unroll
        for (int i = 0; i < 4; i++) { acc2[i][0] = (f32x4)0.f; acc2[i][1] = (f32x4)0.f; }
#pragma unroll
        for (int k0 = 0; k0 < 4; k0++) {
            s16x8 af2[4], bf2[2];
#pragma unroll
            for (int mi = 0; mi < 4; mi++)
                af2[mi] = *(const s16x8*)&s2buf[(wm * 64 + mi * 16 + lr) * 136 + k0 * 32 + lk];
#pragma unroll
            for (int ni = 0; ni < 2; ni++)
                bf2[ni] = *(const s16x8*)&s2buf[128 * 136 + (wn * 32 + ni * 16 + lr) * 136 + k0 * 32 + lk];
#pragma unroll
            for (int mi = 0; mi < 4; mi++)
#pragma unroll
                for (int ni = 0; ni < 2; ni++)
                    acc2[mi][ni] = __builtin_amdgcn_mfma_f32_16x16x32_bf16(af2[mi], bf2[ni], acc2[mi][ni], 0, 0, 0);
        }
#pragma unroll
        for (int mi = 0; mi < 4; mi++) {
#pragma unroll
            for (int r = 0; r < 4; r++) {
                const int row = wm * 64 + mi * 16 + (l >> 4) * 4 + r;
#pragma unroll
                for (int ni = 0; ni < 2; ni++) {
                    const int col = n0 + wn * 32 + ni * 16 + lr;
                    float v2 = acc2[mi][ni][r];
                    if constexpr (F2 == 1) {
                        ((unsigned short*)Out2 + (long)bz * sC)[(long)row * N + col] = f2bf(v2);
                    } else {
                        float g = sigm(v2 + b2[row]);
                        float zv = acc[mi][ni][r];
                        float hv = Hres[(long)bz * sC + (long)row * N + col];
                        (Out2 + (long)bz * sC)[(long)row * N + col] = hv + g * (zv - hv);
                    }
                }
            }
        }
    }
}

// ---------------- channel-LN stats on bf16 input ----------------
__global__ __launch_bounds__(256) void ln_stats_k(const unsigned short* __restrict__ in,
                                                  float* __restrict__ mu,
                                                  float* __restrict__ rs)
{
    __shared__ float s1[4][64], s2[4][64];
    const int tid = threadIdx.x;
    const int p = tid & 63, q = tid >> 6;
    const long posg = (long)blockIdx.x * 64 + p;
    const int b = (int)(posg / L_);
    const int pp = (int)(posg % L_);
    const unsigned short* base = in + ((long)b * C_ + q * 32) * L_ + pp;
    float s = 0.f, sq = 0.f;
#pragma unroll
    for (int i = 0; i < 32; i++) {
        float t = bf2f(base[(long)i * L_]);
        s += t; sq += t * t;
    }
    s1[q][p] = s; s2[q][p] = sq;
    __syncthreads();
    if (q == 0) {
        float ts = s1[0][p] + s1[1][p] + s1[2][p] + s1[3][p];
        float tq = s2[0][p] + s2[1][p] + s2[2][p] + s2[3][p];
        float m = ts * (1.f / 128.f);
        float var = tq * (1.f / 128.f) - m * m;
        mu[posg] = m;
        rs[posg] = rsqrtf(var + EPSf);
    }
}

// ---------------- fused depthwise 3x3 + SiLU (bf16 in/out) ----------------
__global__ __launch_bounds__(256) void dwconvT_k(const unsigned short* __restrict__ in,
                                                 const float* __restrict__ wts,
                                                 const float* __restrict__ bias,
                                                 unsigned short* __restrict__ uo,
                                                 unsigned short* __restrict__ uTo)
{
    __shared__ float t[64][65];
    const long plane = blockIdx.x;
    const int c = (int)(plane & 127);
    const int tid = threadIdx.x;
    const unsigned short* src = in + plane * (long)L_;
#pragma unroll
    for (int ii = 0; ii < 16; ii++) {
        int idx = tid + ii * 256;
        t[idx >> 6][idx & 63] = bf2f(src[idx]);
    }
    float kw[9];
#pragma unroll
    for (int q = 0; q < 9; q++) kw[q] = wts[c * 9 + q];
    const float bc = bias[c];
    __syncthreads();
    float r[16];
#pragma unroll
    for (int ii = 0; ii < 16; ii++) {
        int idx = tid + ii * 256;
        int h = idx >> 6, w2 = idx & 63;
        float acc = bc;
#pragma unroll
        for (int dh = -1; dh <= 1; dh++) {
            int hh = h + dh;
            if ((unsigned)hh >= 64u) continue;
#pragma unroll
            for (int dw = -1; dw <= 1; dw++) {
                int ww2 = w2 + dw;
                if ((unsigned)ww2 >= 64u) continue;
                acc += t[hh][ww2] * kw[(dh + 1) * 3 + (dw + 1)];
            }
        }
        r[ii] = siluf(acc);
    }
    __syncthreads();
    unsigned short* ud = uo + plane * (long)L_;
#pragma unroll
    for (int ii = 0; ii < 16; ii++) {
        int idx = tid + ii * 256;
        t[idx >> 6][idx & 63] = r[ii];
        ud[idx] = f2bf(r[ii]);
    }
    __syncthreads();
    unsigned short* utd = uTo + plane * (long)L_;
#pragma unroll
    for (int ii = 0; ii < 16; ii++) {
        int idx = tid + ii * 256;
        utd[idx] = f2bf(t[idx & 63][idx >> 6]);
    }
}

// ---------------- per-plane 64x64 bf16 transpose-add ----------------
__global__ __launch_bounds__(256) void transpb_k(const unsigned short* __restrict__ src,
                                                 unsigned short* __restrict__ dst)
{
    __shared__ float t[64][65];
    const long plane = blockIdx.x;
    const unsigned short* s = src + plane * (long)L_;
    unsigned short* d = dst + plane * (long)L_;
    const int tid = threadIdx.x;
#pragma unroll
    for (int i = 0; i < 16; i++) {
        int idx = tid + i * 256;
        t[idx >> 6][idx & 63] = bf2f(s[idx]);
    }
    __syncthreads();
#pragma unroll
    for (int i = 0; i < 16; i++) {
        int idx = tid + i * 256;
        int r = idx >> 6, cc = idx & 63;
        float val = t[cc][r] + bf2f(d[idx]);
        d[idx] = f2bf(val);
    }
}

// ---------------- x_dbl projection (bf16 u), k & k+2 fused (scan-order out) ----------------
__global__ __launch_bounds__(256) void xdbl2_k(const unsigned short* __restrict__ u,
                                               const unsigned short* __restrict__ uT,
                                               const float* __restrict__ xw,
                                               float* __restrict__ out)
{
    __shared__ float wsm[2][16][132];
    const int pair = blockIdx.y, b = blockIdx.z;
    const int tid = threadIdx.x;
#pragma unroll
    for (int i = 0; i < 8; i++) {
        int idx = tid * 8 + i;
        wsm[0][idx >> 7][idx & 127] = xw[pair * 2048 + idx];
        wsm[1][idx >> 7][idx & 127] = xw[(pair + 2) * 2048 + idx];
    }
    __syncthreads();
    const int dg = (tid & 3) * 4;
    const int lo = tid >> 2;
    const int pos = blockIdx.x * 64 + lo;
    const unsigned short* usrc = (pair ? uT : u) + (long)b * C_ * L_ + pos;
    float a0[4] = {0.f, 0.f, 0.f, 0.f};
    float a1[4] = {0.f, 0.f, 0.f, 0.f};
#pragma unroll 4
    for (int c = 0; c < C_; c++) {
        float uc = bf2f(usrc[(long)c * L_]);
#pragma unroll
        for (int j = 0; j < 4; j++) {
            a0[j] += wsm[0][dg + j][c] * uc;
            a1[j] += wsm[1][dg + j][c] * uc;
        }
    }
    const long baseA = ((long)(b * K_ + pair) * L_) << 4;
    const long baseB = ((long)(b * K_ + pair + 2) * L_) << 4;
    const int s  = tadr(pos);
    const int s2 = tadr(L_ - 1 - pos);
    *(float4*)(out + baseA + ((long)s  << 4) + dg) = make_float4(a0[0], a0[1], a0[2], a0[3]);
    *(float4*)(out + baseB + ((long)s2 << 4) + dg) = make_float4(a1[0], a1[1], a1[2], a1[3]);
}

// ---------------- scan pass 1 (stores wv bf16; P via exp2 of wv-sum) ----------------
template <bool WV>
__global__ __launch_bounds__(256) void scan_ph1L_k(const float* __restrict__ xdbl,
                                                   const unsigned short* __restrict__ u,
                                                   const unsigned short* __restrict__ uT,
                                                   const float* __restrict__ dtw,
                                                   const float* __restrict__ dtb,
                                                   const float* __restrict__ alogs,
                                                   float* __restrict__ st,
                                                   unsigned short* __restrict__ wvb)
{
    __shared__ float xtf[2][32][12];
    __shared__ float xtb[2][32][12];
    const int bid = blockIdx.x;
    const int jj = bid & 63, kh = (bid >> 6) & 1, b = bid >> 7;
    const int t = threadIdx.x;
    const int kf = kh, kb = kh + 2;
    const float* xf = xdbl + ((long)(b * 4 + kf) << 16);
    const float* xb = xdbl + ((long)(b * 4 + kb) << 16);
    {
        const int q = t & 3, i = (t >> 2) & 31, j2 = t >> 7;
        if (q < 3) {
            const int jf = 2 * jj + j2, jB = 127 - jf;
            const int sf = (((jf & 1) * 32 + i) << 6) | (jf >> 1);
            const int sb = (((jB & 1) * 32 + i) << 6) | (jB >> 1);
            *(float4*)&xtf[j2][i][q * 4] = *(const float4*)(xf + (long)sf * 16 + q * 4);
            *(float4*)&xtb[j2][i][q * 4] = *(const float4*)(xb + (long)sb * 16 + q * 4);
        }
    }
    const int c = t & 127, jh = t >> 7;
    const int jf = 2 * jj + jh, jB = 127 - jf;
    const unsigned short* uplane = (kh ? uT : u) + (long)(b * 128 + c) * L_;
    unsigned ur2[16];
    {
        const unsigned short* up = uplane + jf * 32;
#pragma unroll
        for (int q = 0; q < 4; q++) {
            uint4 a = *(const uint4*)(up + q * 8);
            ur2[q * 4 + 0] = a.x; ur2[q * 4 + 1] = a.y;
            ur2[q * 4 + 2] = a.z; ur2[q * 4 + 3] = a.w;
        }
    }
    __syncthreads();
    unsigned wv2[16];
    // ---- fwd chunk ----
    {
        float dw[8];
#pragma unroll
        for (int r = 0; r < 8; r++) dw[r] = dtw[((kf * 128 + c) << 3) + r];
        const float db = dtb[kf * 128 + c];
        float An[4];
#pragma unroll
        for (int n = 0; n < 4; n++) An[n] = -__expf(alogs[((kf * 128 + c) << 2) + n]);
        float wsum = 0.f;
        float S0 = 0.f, S1 = 0.f, S2 = 0.f, S3 = 0.f;
#pragma unroll
        for (int i = 0; i < 32; i++) {
            float4 x0 = *(const float4*)&xtf[jh][i][0];
            float4 x1 = *(const float4*)&xtf[jh][i][4];
            float4 xs = *(const float4*)&xtf[jh][i][8];
            float z = db + x0.x*dw[0] + x0.y*dw[1] + x0.z*dw[2] + x0.w*dw[3]
                         + x1.x*dw[4] + x1.y*dw[5] + x1.z*dw[6] + x1.w*dw[7];
            float wv = (z > 15.f) ? z * LOG2E : log2f(1.f + __expf(z));
            unsigned short wb = f2bf(wv);
            wv = bf2f(wb);
            if (i & 1) wv2[i >> 1] |= ((unsigned)wb << 16);
            else       wv2[i >> 1]  = (unsigned)wb;
            wsum += wv;
            float dl = wv * LN2f;
            float du = dl * upk(ur2, i);
            float e;
            e = exp2f(wv * An[0]); S0 = e * S0 + du * xs.x;
            e = exp2f(wv * An[1]); S1 = e * S1 + du * xs.y;
            e = exp2f(wv * An[2]); S2 = e * S2 + du * xs.z;
            e = exp2f(wv * An[3]); S3 = e * S3 + du * xs.w;
        }
        float* o = st + ((long)((b * 4 + kf) * 128 + c) << 10) + (jf << 3);
        *(float4*)o = make_float4(exp2f(wsum * An[0]), exp2f(wsum * An[1]),
                                  exp2f(wsum * An[2]), exp2f(wsum * An[3]));
        *(float4*)(o + 4) = make_float4(S0, S1, S2, S3);
        if constexpr (WV) {
            unsigned short* wd = wvb + ((long)((b * 4 + kf) * 128 + c) << 12) + jf * 32;
#pragma unroll
            for (int q = 0; q < 4; q++)
                *(uint4*)(wd + q * 8) = make_uint4(wv2[q*4], wv2[q*4+1], wv2[q*4+2], wv2[q*4+3]);
        }
    }
    // ---- bwd chunk ----
    {
        float dw[8];
#pragma unroll
        for (int r = 0; r < 8; r++) dw[r] = dtw[((kb * 128 + c) << 3) + r];
        const float db = dtb[kb * 128 + c];
        float An[4];
#pragma unroll
        for (int n = 0; n < 4; n++) An[n] = -__expf(alogs[((kb * 128 + c) << 2) + n]);
        float wsum = 0.f;
        float S0 = 0.f, S1 = 0.f, S2 = 0.f, S3 = 0.f;
#pragma unroll
        for (int i = 0; i < 32; i++) {
            float4 x0 = *(const float4*)&xtb[jh][i][0];
            float4 x1 = *(const float4*)&xtb[jh][i][4];
            float4 xs = *(const float4*)&xtb[jh][i][8];
            float z = db + x0.x*dw[0] + x0.y*dw[1] + x0.z*dw[2] + x0.w*dw[3]
                         + x1.x*dw[4] + x1.y*dw[5] + x1.z*dw[6] + x1.w*dw[7];
            float wv = (z > 15.f) ? z * LOG2E : log2f(1.f + __expf(z));
            unsigned short wb = f2bf(wv);
            wv = bf2f(wb);
            if (i & 1) wv2[i >> 1] |= ((unsigned)wb << 16);
            else       wv2[i >> 1]  = (unsigned)wb;
            wsum += wv;
            float dl = wv * LN2f;
            float du = dl * upk(ur2, 31 - i);
            float e;
            e = exp2f(wv * An[0]); S0 = e * S0 + du * xs.x;
            e = exp2f(wv * An[1]); S1 = e * S1 + du * xs.y;
            e = exp2f(wv * An[2]); S2 = e * S2 + du * xs.z;
            e = exp2f(wv * An[3]); S3 = e * S3 + du * xs.w;
        }
        float* o = st + ((long)((b * 4 + kb) * 128 + c) << 10) + (jB << 3);
        *(float4*)o = make_float4(exp2f(wsum * An[0]), exp2f(wsum * An[1]),
                                  exp2f(wsum * An[2]), exp2f(wsum * An[3]));
        *(float4*)(o + 4) = make_float4(S0, S1, S2, S3);
        if constexpr (WV) {
            unsigned short* wd = wvb + ((long)((b * 4 + kb) * 128 + c) << 12) + jB * 32;
#pragma unroll
            for (int q = 0; q < 4; q++)
                *(uint4*)(wd + q * 8) = make_uint4(wv2[q*4], wv2[q*4+1], wv2[q*4+2], wv2[q*4+3]);
        }
    }
}

// ---------------- scan mid: wave scans 128 chunks (2 per lane) ----------------
__global__ __launch_bounds__(256) void scan_mid_k(float* __restrict__ st)
{
    const long t = (long)blockIdx.x * 256 + threadIdx.x;
    const long chain = t >> 6;
    const int ln = (int)(t & 63);
    float* base = st + (chain << 10) + (ln << 4);
    float4 Pa = *(float4*)(base + 0);
    float4 Sa = *(float4*)(base + 4);
    float4 Pb = *(float4*)(base + 8);
    float4 Sb = *(float4*)(base + 12);
    float4 P, S;
    P.x = Pb.x * Pa.x; P.y = Pb.y * Pa.y; P.z = Pb.z * Pa.z; P.w = Pb.w * Pa.w;
    S.x = Sb.x + Pb.x * Sa.x; S.y = Sb.y + Pb.y * Sa.y;
    S.z = Sb.z + Pb.z * Sa.z; S.w = Sb.w + Pb.w * Sa.w;
#pragma unroll
    for (int d = 1; d < 64; d <<= 1) {
        float4 Pu, Su;
        Pu.x = __shfl_up(P.x, d, 64); Pu.y = __shfl_up(P.y, d, 64);
        Pu.z = __shfl_up(P.z, d, 64); Pu.w = __shfl_up(P.w, d, 64);
        Su.x = __shfl_up(S.x, d, 64); Su.y = __shfl_up(S.y, d, 64);
        Su.z = __shfl_up(S.z, d, 64); Su.w = __shfl_up(S.w, d, 64);
        if (ln >= d) {
            S.x += P.x * Su.x; S.y += P.y * Su.y;
            S.z += P.z * Su.z; S.w += P.w * Su.w;
            P.x *= Pu.x; P.y *= Pu.y; P.z *= Pu.z; P.w *= Pu.w;
        }
    }
    float4 E;
    E.x = __shfl_up(S.x, 1, 64); E.y = __shfl_up(S.y, 1, 64);
    E.z = __shfl_up(S.z, 1, 64); E.w = __shfl_up(S.w, 1, 64);
    if (ln == 0) { E.x = 0.f; E.y = 0.f; E.z = 0.f; E.w = 0.f; }
    float4 E1;
    E1.x = Sa.x + Pa.x * E.x; E1.y = Sa.y + Pa.y * E.y;
    E1.z = Sa.z + Pa.z * E.z; E1.w = Sa.w + Pa.w * E.w;
    *(float4*)(base + 4)  = E;
    *(float4*)(base + 12) = E1;
}

// ---------------- scan pass 2: y in registers, direct bf16 global write ----------------
template <bool WV>
__global__ __launch_bounds__(256) void scan_ph2L_k(const float* __restrict__ xdbl,
                                                   const unsigned short* __restrict__ u,
                                                   const unsigned short* __restrict__ uT,
                                                   const float* __restrict__ dtw,
                                                   const float* __restrict__ dtb,
                                                   const float* __restrict__ alogs,
                                                   const float* __restrict__ Dsp,
                                                   const float* __restrict__ st,
                                                   const unsigned short* __restrict__ wvb,
                                                   unsigned short* __restrict__ Y0,
                                                   unsigned short* __restrict__ Yt)
{
    constexpr int TS = WV ? 8 : 16;
    __shared__ float xtf[2][32][TS];
    __shared__ float xtb[2][32][TS];
    const int bid = blockIdx.x;
    const int jj = bid & 63, kh = (bid >> 6) & 1, b = bid >> 7;
    const int t = threadIdx.x;
    const int kf = kh, kb = kh + 2;
    const float* xf = xdbl + ((long)(b * 4 + kf) << 16);
    const float* xb = xdbl + ((long)(b * 4 + kb) << 16);
    if constexpr (WV) {
        const int tt = t & 127;
        const int q = tt & 1, i = (tt >> 1) & 31, j2 = tt >> 6;
        const int jf2 = 2 * jj + j2, jB2 = 127 - jf2;
        if (t < 128) {
            const int sf = (((jf2 & 1) * 32 + i) << 6) | (jf2 >> 1);
            *(float4*)&xtf[j2][i][q * 4] = *(const float4*)(xf + (long)sf * 16 + 8 + q * 4);
        } else {
            const int sb = (((jB2 & 1) * 32 + i) << 6) | (jB2 >> 1);
            *(float4*)&xtb[j2][i][q * 4] = *(const float4*)(xb + (long)sb * 16 + 8 + q * 4);
        }
    } else {
        const int q = t & 3, i = (t >> 2) & 31, j2 = t >> 7;
        const int jf2 = 2 * jj + j2, jB2 = 127 - jf2;
        const int sf = (((jf2 & 1) * 32 + i) << 6) | (jf2 >> 1);
        const int sb = (((jB2 & 1) * 32 + i) << 6) | (jB2 >> 1);
        *(float4*)&xtf[j2][i][q * 4] = *(const float4*)(xf + (long)sf * 16 + q * 4);
        *(float4*)&xtb[j2][i][q * 4] = *(const float4*)(xb + (long)sb * 16 + q * 4);
    }
    const int c = t & 127, jh = t >> 7;
    const int jf = 2 * jj + jh, jB = 127 - jf;
    const unsigned short* uplane = (kh ? uT : u) + (long)(b * 128 + c) * L_;
    unsigned ur2[16];
    {
        const unsigned short* up = uplane + jf * 32;
#pragma unroll
        for (int q = 0; q < 4; q++) {
            uint4 a = *(const uint4*)(up + q * 8);
            ur2[q * 4 + 0] = a.x; ur2[q * 4 + 1] = a.y;
            ur2[q * 4 + 2] = a.z; ur2[q * 4 + 3] = a.w;
        }
    }
    __syncthreads();
    float yreg[32];
    unsigned wv2[16];
    // ---- fwd chunk ----
    {
        float An[4];
#pragma unroll
        for (int n = 0; n < 4; n++) An[n] = -__expf(alogs[((kf * 128 + c) << 2) + n]);
        const float Dc = Dsp[kf * 128 + c];
        float dw[8]; float db = 0.f;
        if constexpr (!WV) {
#pragma unroll
            for (int r = 0; r < 8; r++) dw[r] = dtw[((kf * 128 + c) << 3) + r];
            db = dtb[kf * 128 + c];
        } else {
            const unsigned short* wp2 = wvb + ((long)((b * 4 + kf) * 128 + c) << 12) + jf * 32;
#pragma unroll
            for (int q = 0; q < 4; q++) {
                uint4 a = *(const uint4*)(wp2 + q * 8);
                wv2[q * 4 + 0] = a.x; wv2[q * 4 + 1] = a.y;
                wv2[q * 4 + 2] = a.z; wv2[q * 4 + 3] = a.w;
            }
        }
        float4 H = *(const float4*)(st + ((long)((b * 4 + kf) * 128 + c) << 10) + (jf << 3) + 4);
        float h0 = H.x, h1 = H.y, h2 = H.z, h3 = H.w;
#pragma unroll
        for (int i = 0; i < 32; i++) {
            float wv;
            if constexpr (WV) {
                wv = upk(wv2, i);
            } else {
                float4 x0 = *(const float4*)&xtf[jh][i][0];
                float4 x1 = *(const float4*)&xtf[jh][i][4];
                float z = db + x0.x*dw[0] + x0.y*dw[1] + x0.z*dw[2] + x0.w*dw[3]
                             + x1.x*dw[4] + x1.y*dw[5] + x1.z*dw[6] + x1.w*dw[7];
                wv = (z > 15.f) ? z * LOG2E : log2f(1.f + __expf(z));
            }
            float4 xs = *(const float4*)&xtf[jh][i][TS - 8];
            float4 xc = *(const float4*)&xtf[jh][i][TS - 4];
            float uv = upk(ur2, i);
            float dl = wv * LN2f;
            float du = dl * uv;
            float e;
            e = exp2f(wv * An[0]); h0 = e * h0 + du * xs.x;
            e = exp2f(wv * An[1]); h1 = e * h1 + du * xs.y;
            e = exp2f(wv * An[2]); h2 = e * h2 + du * xs.z;
            e = exp2f(wv * An[3]); h3 = e * h3 + du * xs.w;
            yreg[i] = h0 * xc.x + h1 * xc.y + h2 * xc.z + h3 * xc.w + Dc * uv;
        }
    }
    // ---- bwd chunk (same 32 output positions, reversed) ----
    {
        float An[4];
#pragma unroll
        for (int n = 0; n < 4; n++) An[n] = -__expf(alogs[((kb * 128 + c) << 2) + n]);
        const float Dc = Dsp[kb * 128 + c];
        float dw[8]; float db = 0.f;
        if constexpr (!WV) {
#pragma unroll
            for (int r = 0; r < 8; r++) dw[r] = dtw[((kb * 128 + c) << 3) + r];
            db = dtb[kb * 128 + c];
        } else {
            const unsigned short* wp2 = wvb + ((long)((b * 4 + kb) * 128 + c) << 12) + jB * 32;
#pragma unroll
            for (int q = 0; q < 4; q++) {
                uint4 a = *(const uint4*)(wp2 + q * 8);
                wv2[q * 4 + 0] = a.x; wv2[q * 4 + 1] = a.y;
                wv2[q * 4 + 2] = a.z; wv2[q * 4 + 3] = a.w;
            }
        }
        float4 H = *(const float4*)(st + ((long)((b * 4 + kb) * 128 + c) << 10) + (jB << 3) + 4);
        float h0 = H.x, h1 = H.y, h2 = H.z, h3 = H.w;
#pragma unroll
        for (int i = 0; i < 32; i++) {
            float wv;
            if constexpr (WV) {
                wv = upk(wv2, i);
            } else {
                float4 x0 = *(const float4*)&xtb[jh][i][0];
                float4 x1 = *(const float4*)&xtb[jh][i][4];
                float z = db + x0.x*dw[0] + x0.y*dw[1] + x0.z*dw[2] + x0.w*dw[3]
                             + x1.x*dw[4] + x1.y*dw[5] + x1.z*dw[6] + x1.w*dw[7];
                wv = (z > 15.f) ? z * LOG2E : log2f(1.f + __expf(z));
            }
            float4 xs = *(const float4*)&xtb[jh][i][TS - 8];
            float4 xc = *(const float4*)&xtb[jh][i][TS - 4];
            float uv = upk(ur2, 31 - i);
            float dl = wv * LN2f;
            float du = dl * uv;
            float e;
            e = exp2f(wv * An[0]); h0 = e * h0 + du * xs.x;
            e = exp2f(wv * An[1]); h1 = e * h1 + du * xs.y;
            e = exp2f(wv * An[2]); h2 = e * h2 + du * xs.z;
            e = exp2f(wv * An[3]); h3 = e * h3 + du * xs.w;
            yreg[31 - i] += h0 * xc.x + h1 * xc.y + h2 * xc.z + h3 * xc.w + Dc * uv;
        }
    }
    unsigned short* ydst = (kh ? Yt : Y0) + (long)(b * 128 + c) * L_ + jf * 32;
#pragma unroll
    for (int q = 0; q < 8; q++) {
        ushort4 v;
        v.x = f2bf(yreg[q * 4 + 0]); v.y = f2bf(yreg[q * 4 + 1]);
        v.z = f2bf(yreg[q * 4 + 2]); v.w = f2bf(yreg[q * 4 + 3]);
        *(ushort4*)(ydst + q * 4) = v;
    }
}

// ---------------- launch ----------------
extern "C" void kernel_launch(void* const* d_in, const int* in_sizes, int n_in,
                              void* d_out, int out_size, void* d_ws, size_t ws_size,
                              hipStream_t stream)
{
    const float* h_in      = (const float*)d_in[0];
    const float* x_in      = (const float*)d_in[4];
    const float* in_proj_w = (const float*)d_in[5];
    const float* in_proj_b = (const float*)d_in[6];
    const float* ln1_g     = (const float*)d_in[7];
    const float* ln1_b     = (const float*)d_in[8];
    const float* ssm_in_w  = (const float*)d_in[9];
    const float* conv_w    = (const float*)d_in[10];
    const float* conv_b    = (const float*)d_in[11];
    const float* x_proj_w  = (const float*)d_in[12];
    const float* dt_w      = (const float*)d_in[13];
    const float* dt_b      = (const float*)d_in[14];
    const float* A_logs    = (const float*)d_in[15];
    const float* Dsp       = (const float*)d_in[16];
    const float* outnorm_g = (const float*)d_in[17];
    const float* outnorm_b = (const float*)d_in[18];
    const float* out_proj_w= (const float*)d_in[19];
    const float* ln2_g     = (const float*)d_in[20];
    const float* ln2_b     = (const float*)d_in[21];
    const float* fc1_w     = (const float*)d_in[22];
    const float* fc1_b     = (const float*)d_in[23];
    const float* fc2_w     = (const float*)d_in[24];
    const float* fc2_b     = (const float*)d_in[25];
    const float* gate_w    = (const float*)d_in[26];
    const float* gate_b    = (const float*)d_in[27];

    float* ws   = (float*)d_ws;
    float* fz   = ws;              // feat -> z (fp32)
    float* ubuf = ws + SZ1;        // u (bf16) ; MLP hidden (bf16) overlays
    float* tbuf = ws + 2 * SZ1;    // u0(bf16) -> Y0/merged-y (bf16)
    float* ybuf = ws + 3 * SZ1;    // uT(bf16)
    float* xdbl = ws + 4 * SZ1;    // [B,K,L(scan order),16] fp32
    float* stbf = ws + 4 * SZ1 + 2097152;           // chunk states
    float* muB  = stbf;            // LN stats overlay
    float* rsB  = stbf + 32768;
    const long wvOff = 4 * SZ1 + 2097152 + 4194304;
    unsigned short* wvb = (unsigned short*)(ws + wvOff);
    const bool wvOK = (ws_size / 4) >= (size_t)(wvOff + 8388608);
    float* mbuf = ubuf;            // MLP hidden, bf16, all 8 batches
    float* gbuf = (float*)d_out;   // Yt(bf16) -> ln2out(bf16) -> final out

    unsigned short* u_u  = (unsigned short*)ubuf;
    unsigned short* u0_u = (unsigned short*)tbuf;
    unsigned short* uT_u = (unsigned short*)ybuf;
    unsigned short* y0_u = (unsigned short*)tbuf;
    unsigned short* yt_u = (unsigned short*)gbuf;

    const dim3 blk(256);
    const long sBC = (long)C_ * L_;
    const long sX  = (long)CIN_ * L_;
    const long sM  = (long)DFF_ * L_;

    // 1) feat = in_proj@concat + b (fz); fused ln1 + ssm_in -> u0 (tbuf bf16)
    gemm_k<64, false, true, false, false, false, true, false, true, false, false, 1>
        <<<dim3(64, 1, 8), blk, 0, stream>>>(
        in_proj_w, h_in, sBC, x_in, sX, 128, in_proj_b,
        nullptr, nullptr, nullptr, nullptr, nullptr, ln1_g, ln1_b,
        fz, sBC, 128, L_, 320,
        ssm_in_w, nullptr, nullptr, tbuf);
    // 2) u = silu(dwconv(u0)+b) -> ubuf ; u^T -> ybuf
    dwconvT_k<<<dim3(1024), blk, 0, stream>>>(u0_u, conv_w, conv_b, u_u, uT_u);
    // 3) x_dbl, k & k+2 fused
    xdbl2_k<<<dim3(64, 2, 8), blk, 0, stream>>>(u_u, uT_u, x_proj_w, xdbl);
    // 4-6) scan
    if (wvOK) {
        scan_ph1L_k<true><<<dim3(1024), blk, 0, stream>>>(xdbl, u_u, uT_u, dt_w, dt_b,
                                                          A_logs, stbf, wvb);
        scan_mid_k<<<dim3(1024), blk, 0, stream>>>(stbf);
        scan_ph2L_k<true><<<dim3(1024), blk, 0, stream>>>(xdbl, u_u, uT_u, dt_w, dt_b,
                                                          A_logs, Dsp, stbf, wvb, y0_u, yt_u);
    } else {
        scan_ph1L_k<false><<<dim3(1024), blk, 0, stream>>>(xdbl, u_u, uT_u, dt_w, dt_b,
                                                           A_logs, stbf, wvb);
        scan_mid_k<<<dim3(1024), blk, 0, stream>>>(stbf);
        scan_ph2L_k<false><<<dim3(1024), blk, 0, stream>>>(xdbl, u_u, uT_u, dt_w, dt_b,
                                                           A_logs, Dsp, stbf, wvb, y0_u, yt_u);
    }
    // 7) merged y: tbuf += transpose(gbuf)
    transpb_k<<<dim3(1024), blk, 0, stream>>>(yt_u, y0_u);
    // 8) outnorm stats
    ln_stats_k<<<dim3(512), blk, 0, stream>>>(y0_u, muB, rsB);
    // 9) z = feat + out_proj @ outnorm(y) [XBF+XLN]; fused ln2 -> gbuf (bf16)
    gemm_k<64, true, false, false, false, false, false, true, true, true, false, 0>
        <<<dim3(64, 1, 8), blk, 0, stream>>>(
        out_proj_w, tbuf, sBC, nullptr, 0, 1 << 30, nullptr,
        muB, rsB, outnorm_g, outnorm_b, gbuf, ln2_g, ln2_b,
        fz, sBC, 128, L_, 128,
        nullptr, nullptr, nullptr, nullptr);
    // 10) fc1: all 8 batches, X = ln2out bf16 -> hidden bf16
    gemm_k<128, false, true, false, false, false, false, false, false, true, true, 0>
        <<<dim3(32, 4, 8), blk, 0, stream>>>(
        fc1_w, gbuf, sBC, nullptr, 0, 1 << 30, fc1_b,
        nullptr, nullptr, nullptr, nullptr, nullptr, nullptr, nullptr,
        mbuf, sM, 512, L_, 128,
        nullptr, nullptr, nullptr, nullptr);
    // 11) fc2 (+gelu, ACC z) ; fused gate GEMM + blend -> d_out
    gemm_k<64, true, true, true, false, false, false, false, false, true, false, 2>
        <<<dim3(64, 1, 8), blk, 0, stream>>>(
        fc2_w, mbuf, sM, nullptr, 0, 1 << 30, fc2_b,
        nullptr, nullptr, nullptr, nullptr, nullptr, nullptr, nullptr,
        fz, sBC, 128, L_, 512,
        gate_w, gate_b, h_in, (float*)d_out);
}